// Round 13
// baseline (313.105 us; speedup 1.0000x reference)
//
#include <hip/hip_runtime.h>

// Frequency-domain room sim, 3-kernel phase split.
//   SF = DFT(sound_field) per cell (unnormalized); per block b:
//     T = clip(res,0,1) * (SF + DFT(env_b));  mic_b = IDFT(T[mic])/1024;
//     SF = box3x3x3(T)   (pointwise per bin -> recursion independent per bin)
// P1: 16 cells/WG (grid 4096). Two 8-cell mixed-radix 8*8*8*2 FFT batches
//     (2 packed float4 buffers, 32KB, reused), each extracted into a padded
//     fp16 LDS staging tile [1024 slots][8 pairs] (36KB). Final sweep stores
//     32B/lane FULLY CONTIGUOUS to chunk-major Et[b][chunk][slot][8]
//     (chunk = pair/8). TFt: 16 cells = 64B/row/lane = full-line stores.
//     This kills the 16B scattered-sector store wall (rounds 5-12 invariant).
// P2: 512 WGs x 1024 threads. Thread owns 4-z slab; z via shfl, y/x via 32KB
//     swizzled LDS. Et read: 4 lanes share a 32B entry (2x ideal trans).
// P3: 16 inverse FFTs of the mic spectra.

#define NFFT   1024
#define NF     513
#define NKP    257
#define NCELLS 4096
#define PI2    6.28318530717958647692f
#define RT2    0.70710678118654752f

__device__ __forceinline__ int SW(int i) {
    return i ^ ((i >> 4) & 7) ^ ((i >> 7) & 7);
}
__device__ __forceinline__ int slotof(int k) {
    return ((k & 7) << 7) | (((k >> 3) & 7) << 4) | (((k >> 6) & 7) << 1) | ((k >> 9) & 1);
}
__device__ __forceinline__ float clip01(float v) { return fminf(fmaxf(v, 0.0f), 1.0f); }
__device__ __forceinline__ unsigned pkh2(float a, float b) {
    union { _Float16 h[2]; unsigned u; } z;
    z.h[0] = (_Float16)a; z.h[1] = (_Float16)b;
    return z.u;
}
__device__ __forceinline__ float h2lo(unsigned u) {
    union { unsigned u; _Float16 h[2]; } z; z.u = u; return (float)z.h[0];
}
__device__ __forceinline__ float h2hi(unsigned u) {
    union { unsigned u; _Float16 h[2]; } z; z.u = u; return (float)z.h[1];
}
__device__ __forceinline__ unsigned cmp4(const uint4& v, int c) {
    return c == 0 ? v.x : c == 1 ? v.y : c == 2 ? v.z : v.w;
}
__device__ __forceinline__ float4 f4add(float4 a, float4 b) {
    return make_float4(a.x + b.x, a.y + b.y, a.z + b.z, a.w + b.w);
}
__device__ __forceinline__ float4 f4sub(float4 a, float4 b) {
    return make_float4(a.x - b.x, a.y - b.y, a.z - b.z, a.w - b.w);
}
__device__ __forceinline__ float4 cmul2(float4 d, float2 w) {
    return make_float4(d.x * w.x - d.y * w.y, d.x * w.y + d.y * w.x,
                       d.z * w.x - d.w * w.y, d.z * w.y + d.w * w.x);
}
__device__ __forceinline__ float4 nI(float4 v) { return make_float4(v.y, -v.x, v.w, -v.z); }
__device__ __forceinline__ float4 pI(float4 v) { return make_float4(-v.y, v.x, -v.w, v.z); }
__device__ __forceinline__ float4 w81(float4 v) {
    return make_float4(RT2 * (v.x + v.y), RT2 * (v.y - v.x),
                       RT2 * (v.z + v.w), RT2 * (v.w - v.z));
}
__device__ __forceinline__ float4 w83(float4 v) {
    return make_float4(RT2 * (v.y - v.x), RT2 * (-v.x - v.y),
                       RT2 * (v.w - v.z), RT2 * (-v.z - v.w));
}

__device__ __forceinline__ void dft8(float4* a) {
    float4 c0 = f4add(a[0], a[4]), c1 = f4add(a[1], a[5]);
    float4 c2 = f4add(a[2], a[6]), c3 = f4add(a[3], a[7]);
    float4 d0 = f4sub(a[0], a[4]);
    float4 d1 = w81(f4sub(a[1], a[5]));
    float4 d2 = nI (f4sub(a[2], a[6]));
    float4 d3 = w83(f4sub(a[3], a[7]));
    float4 t0 = f4add(c0, c2), t1 = f4add(c1, c3);
    float4 t2 = f4sub(c0, c2), t3 = f4sub(c1, c3);
    float4 s0 = f4add(d0, d2), s1 = f4add(d1, d3);
    float4 s2 = f4sub(d0, d2), s3 = f4sub(d1, d3);
    a[0] = f4add(t0, t1);      a[4] = f4sub(t0, t1);
    a[2] = f4add(t2, nI(t3));  a[6] = f4add(t2, pI(t3));
    a[1] = f4add(s0, s1);      a[5] = f4sub(s0, s1);
    a[3] = f4add(s2, nI(s3));  a[7] = f4add(s2, pI(s3));
}

__device__ __forceinline__ void twiddle7(float4* a, int j, float invL) {
    float sv, cv;
    __sincosf(-PI2 * (float)j * invL, &sv, &cv);
    float2 w1 = make_float2(cv, sv), wp = w1;
    a[1] = cmul2(a[1], wp);
    #pragma unroll
    for (int p = 2; p < 8; ++p) {
        wp = make_float2(wp.x * w1.x - wp.y * w1.y, wp.x * w1.y + wp.y * w1.x);
        a[p] = cmul2(a[p], wp);
    }
}

// ---------------- P1 ----------------
// Grid 4096 = 16 blocks x 256 WGs. WG owns 16 cells (8 pairs = chunk c0/16).
__global__ __launch_bounds__(256, 2) void k_p1(
    const float* __restrict__ tf, const float* __restrict__ imp,
    const float* __restrict__ noise, unsigned* __restrict__ Et,
    unsigned* __restrict__ TFt)
{
    __shared__ float4 FD[2][1024];       // 32 KB work (reused per batch)
    __shared__ unsigned stag[1024 * 9];  // 36 KB padded staging [slot][8 pairs]

    const int tid = threadIdx.x;
    const int bid = blockIdx.x;
    const int w   = ((bid & 7) << 9) | (bid >> 3);    // XCD-chunked swizzle
    const int b   = w >> 8;
    const int c0  = (w & 255) << 4;                   // 16-cell base
    const int buf = tid >> 7, j1 = tid & 127;

    // per-thread twiddles (same for both batches)
    float2 tu0[3], tu1[3], tl[3];
    {
        float s, c;
        __sincosf(-PI2 * (1.0f / 1024.0f) * (float)j1, &s, &c);           tu0[0] = make_float2(c, s);
        __sincosf(-PI2 * (1.0f / 1024.0f) * (float)(j1 & 15), &s, &c);    // placeholder reuse below
        tu0[1] = make_float2(c, s);
        __sincosf(-PI2 * (1.0f / 1024.0f) * (float)(j1 & 1), &s, &c);
        tu0[2] = make_float2(c, s);
    }

    #pragma unroll 1
    for (int bb = 0; bb < 2; ++bb) {
        const int cb = c0 + 8 * bb + 4 * buf;
        if (bb) __syncthreads();         // prior extract must finish reading FD

        // ---- env + pass1 (L=1024, stride 128) from registers ----
        {
            const float* nz = noise + ((size_t)b * NCELLS + cb) * (size_t)NFFT;
            float nzv[32];
            #pragma unroll
            for (int m = 0; m < 8; ++m) {
                #pragma unroll
                for (int cc = 0; cc < 4; ++cc)
                    nzv[4 * m + cc] = nz[cc * NFFT + j1 + (m << 7)];
            }
            const float* ipr = imp + ((size_t)b * NCELLS + cb) * 16;
            float4 a[8];
            #pragma unroll
            for (int m = 0; m < 8; ++m) {
                int n = j1 + (m << 7);
                float coord = (n + 0.5f) * (16.0f / 1024.0f) - 0.5f;
                coord = fminf(fmaxf(coord, 0.0f), 15.0f);
                int lo = (int)coord;
                int hi = lo + 1 > 15 ? 15 : lo + 1;
                float wl = coord - (float)lo, wh = 1.0f - wl;
                float4 e;
                e.x = clip01(ipr[lo]      * wh + ipr[hi]      * wl) * nzv[4 * m + 0];
                e.y = clip01(ipr[16 + lo] * wh + ipr[16 + hi] * wl) * nzv[4 * m + 1];
                e.z = clip01(ipr[32 + lo] * wh + ipr[32 + hi] * wl) * nzv[4 * m + 2];
                e.w = clip01(ipr[48 + lo] * wh + ipr[48 + hi] * wl) * nzv[4 * m + 3];
                a[m] = e;
            }
            dft8(a);
            twiddle7(a, j1, 1.0f / 1024.0f);
            #pragma unroll
            for (int p = 0; p < 8; ++p) FD[buf][SW(j1 + (p << 7))] = a[p];
        }
        __syncthreads();

        // ---- pass2: L=128, stride 16 ----
        {
            const int idx0 = ((j1 >> 4) << 7) + (j1 & 15);
            float4 a[8];
            #pragma unroll
            for (int m = 0; m < 8; ++m) a[m] = FD[buf][SW(idx0 + (m << 4))];
            dft8(a);
            twiddle7(a, j1 & 15, 1.0f / 128.0f);
            #pragma unroll
            for (int p = 0; p < 8; ++p) FD[buf][SW(idx0 + (p << 4))] = a[p];
        }
        __syncthreads();

        // ---- pass3: L=16, stride 2 ----
        {
            const int idx0 = ((j1 >> 1) << 4) + (j1 & 1);
            float4 a[8];
            #pragma unroll
            for (int m = 0; m < 8; ++m) a[m] = FD[buf][SW(idx0 + (m << 1))];
            dft8(a);
            twiddle7(a, j1 & 1, 1.0f / 16.0f);
            #pragma unroll
            for (int p = 0; p < 8; ++p) FD[buf][SW(idx0 + (p << 1))] = a[p];
        }
        __syncthreads();

        // ---- pass4 (radix-2) fused into fp16 extract -> staging tile ----
        // batch bb fills staging columns 4bb .. 4bb+3
        #pragma unroll
        for (int it = 0; it < 2; ++it) {
            int p = tid + (it << 8);
            float4 A0 = FD[0][SW(2 * p)], B0 = FD[0][SW(2 * p + 1)];
            float4 A1 = FD[1][SW(2 * p)], B1 = FD[1][SW(2 * p + 1)];
            float4 y00 = f4add(A0, B0), y10 = f4sub(A0, B0);
            float4 y01 = f4add(A1, B1), y11 = f4sub(A1, B1);
            int r0 = (2 * p) * 9 + 4 * bb;
            int r1 = (2 * p + 1) * 9 + 4 * bb;
            stag[r0 + 0] = pkh2(y00.x, y00.y);
            stag[r0 + 1] = pkh2(y00.z, y00.w);
            stag[r0 + 2] = pkh2(y01.x, y01.y);
            stag[r0 + 3] = pkh2(y01.z, y01.w);
            stag[r1 + 0] = pkh2(y10.x, y10.y);
            stag[r1 + 1] = pkh2(y10.z, y10.w);
            stag[r1 + 2] = pkh2(y11.x, y11.y);
            stag[r1 + 3] = pkh2(y11.z, y11.w);
        }
    }
    __syncthreads();

    // ---- coalesced store sweep: Et[b][chunk=c0/16][slot][8 pairs] ----
    // lane handles slot s: 32B contiguous; wave = 2KB dense.
    {
        unsigned* base = Et + (((size_t)b * 256 + (c0 >> 4)) * 1024) * 8;
        #pragma unroll
        for (int it = 0; it < 4; ++it) {
            int s = tid + (it << 8);
            uint4 lo = { stag[s * 9 + 0], stag[s * 9 + 1], stag[s * 9 + 2], stag[s * 9 + 3] };
            uint4 hi = { stag[s * 9 + 4], stag[s * 9 + 5], stag[s * 9 + 6], stag[s * 9 + 7] };
            *(uint4*)(base + (size_t)s * 8)     = lo;
            *(uint4*)(base + (size_t)s * 8 + 4) = hi;
        }
    }

    // ---- tf: clip + pack bin pairs for 16 cells (64B/lane full-line) ----
    {
        const float* rbase = tf + ((size_t)b * NCELLS + c0) * NF;
        for (int kp = tid; kp < NKP; kp += 256) {
            bool hv = kp < 256;
            uint4 u[4];
            #pragma unroll
            for (int g = 0; g < 4; ++g) {
                unsigned vv[4];
                #pragma unroll
                for (int cq = 0; cq < 4; ++cq) {
                    const float* rr = rbase + (size_t)(4 * g + cq) * NF;
                    vv[cq] = pkh2(clip01(rr[2 * kp]), hv ? clip01(rr[2 * kp + 1]) : 0.0f);
                }
                u[g] = make_uint4(vv[0], vv[1], vv[2], vv[3]);
            }
            unsigned* dst = TFt + ((size_t)b * NKP + kp) * NCELLS + c0;
            *(uint4*)(dst)      = u[0];
            *(uint4*)(dst + 4)  = u[1];
            *(uint4*)(dst + 8)  = u[2];
            *(uint4*)(dst + 12) = u[3];
        }
    }
}

// ---------------- P2 ----------------
// Grid 512 x 1024 threads. Thread q: x = q>>6, y = (q>>2)&15, z-slab (q&3)*4;
// pairs 2q,2q+1 -> Et chunk q>>2, entry offset 2*(q&3). WG0 = bins {0,512}.
__global__ __launch_bounds__(1024, 8) void k_p2(
    const unsigned* __restrict__ Et, const unsigned* __restrict__ TFt,
    float2* __restrict__ ms)
{
    __shared__ float2 Sz[4096];        // 32 KB

    const int q    = threadIdx.x;
    const int lane = q & 63;
    const int k    = blockIdx.x;
    const bool dual = (k == 0);
    const int kp  = dual ? 0 : (k >> 1);
    const int sel = dual ? 0 : (k & 1);
    const int rA  = dual ? 0 : slotof(k);
    const int rB  = dual ? 1 : slotof((1024 - k) & 1023);
    const int x = q >> 6, y = (q >> 2) & 15, zs = (q & 3) << 2;

    #define AX(qq, dz) (((qq) << 2) | ((dz) ^ ((qq) & 3) ^ (((qq) >> 2) & 3)))

    float2 SF[4];
    #pragma unroll
    for (int dz = 0; dz < 4; ++dz) SF[dz] = make_float2(0.f, 0.f);

    #pragma unroll 1
    for (int b = 0; b < 16; ++b) {
        const size_t chunkbase = ((size_t)b * 256 + (q >> 2)) * 1024;
        const uint2 ea = *(const uint2*)(Et + (chunkbase + rA) * 8 + 2 * (q & 3));
        const uint2 eb = *(const uint2*)(Et + (chunkbase + rB) * 8 + 2 * (q & 3));
        const uint4 tp = *(const uint4*)(TFt + ((size_t)b * NKP + kp) * NCELLS + 4 * q);
        uint4 tp2;
        if (dual) tp2 = *(const uint4*)(TFt + ((size_t)b * NKP + 256) * NCELLS + 4 * q);

        float2 T[4];
        if (!dual) {
            #pragma unroll
            for (int j = 0; j < 2; ++j) {
                unsigned fu = j ? ea.y : ea.x;
                unsigned gu = j ? eb.y : eb.x;
                float fr = h2lo(fu), fi = h2hi(fu);
                float gr = h2lo(gu), gi = h2hi(gu);
                float ear = 0.5f * (fr + gr), eai = 0.5f * (fi - gi);
                float ebr = 0.5f * (fi + gi), ebi = 0.5f * (gr - fr);
                unsigned te = cmp4(tp, 2 * j);
                unsigned to = cmp4(tp, 2 * j + 1);
                float re_ = sel ? h2hi(te) : h2lo(te);
                float ro_ = sel ? h2hi(to) : h2lo(to);
                T[2 * j]     = make_float2(re_ * (SF[2 * j].x + ear),
                                           re_ * (SF[2 * j].y + eai));
                T[2 * j + 1] = make_float2(ro_ * (SF[2 * j + 1].x + ebr),
                                           ro_ * (SF[2 * j + 1].y + ebi));
            }
        } else {
            #pragma unroll
            for (int dz = 0; dz < 4; ++dz) {
                unsigned fu = (dz >> 1) ? ea.y : ea.x;
                unsigned gu = (dz >> 1) ? eb.y : eb.x;
                float e0   = (dz & 1) ? h2hi(fu) : h2lo(fu);
                float e512 = (dz & 1) ? h2hi(gu) : h2lo(gu);
                float tA = h2lo(cmp4(tp, dz));
                float tB = h2lo(cmp4(tp2, dz));
                T[dz] = make_float2(tA * (SF[dz].x + e0),
                                    tB * (SF[dz].y + e512));
            }
        }
        if (q == 546) {                 // cell (8,8,8)
            if (dual) {
                ms[b * NF + 0]   = make_float2(T[0].x, 0.0f);
                ms[b * NF + 512] = make_float2(T[0].y, 0.0f);
            } else {
                ms[b * NF + k] = T[0];
            }
        }

        // z-sum: slab-internal + shfl partners q-1 / q+1
        float2 D, U;
        D.x = __shfl(T[3].x, lane - 1, 64); D.y = __shfl(T[3].y, lane - 1, 64);
        U.x = __shfl(T[0].x, lane + 1, 64); U.y = __shfl(T[0].y, lane + 1, 64);
        float2 Z[4];
        Z[0] = make_float2(T[0].x + T[1].x + (zs > 0 ? D.x : 0.f),
                           T[0].y + T[1].y + (zs > 0 ? D.y : 0.f));
        Z[1] = make_float2(T[0].x + T[1].x + T[2].x, T[0].y + T[1].y + T[2].y);
        Z[2] = make_float2(T[1].x + T[2].x + T[3].x, T[1].y + T[2].y + T[3].y);
        Z[3] = make_float2(T[2].x + T[3].x + (zs < 12 ? U.x : 0.f),
                           T[2].y + T[3].y + (zs < 12 ? U.y : 0.f));

        // y-sum via LDS (neighbor q +- 4)
        #pragma unroll
        for (int dz = 0; dz < 4; ++dz) Sz[AX(q, dz)] = Z[dz];
        __syncthreads();
        #pragma unroll
        for (int dz = 0; dz < 4; ++dz) {
            float2 s = Z[dz];
            if (y > 0)  { float2 u = Sz[AX(q - 4, dz)]; s.x += u.x; s.y += u.y; }
            if (y < 15) { float2 u = Sz[AX(q + 4, dz)]; s.x += u.x; s.y += u.y; }
            Z[dz] = s;
        }
        __syncthreads();
        // x-sum via LDS (neighbor q +- 64)
        #pragma unroll
        for (int dz = 0; dz < 4; ++dz) Sz[AX(q, dz)] = Z[dz];
        __syncthreads();
        #pragma unroll
        for (int dz = 0; dz < 4; ++dz) {
            float2 s = Z[dz];
            if (x > 0)  { float2 u = Sz[AX(q - 64, dz)]; s.x += u.x; s.y += u.y; }
            if (x < 15) { float2 u = Sz[AX(q + 64, dz)]; s.x += u.x; s.y += u.y; }
            SF[dz] = s;
        }
        __syncthreads();
    }
    #undef AX
}

// ---------------- P3 ----------------
__device__ __forceinline__ int pd(int i) { return i + (i >> 5); }

__global__ __launch_bounds__(256) void k_p3(
    const float2* __restrict__ ms, float* __restrict__ out)
{
    __shared__ float2 FD[1056];
    const int b = blockIdx.x, tid = threadIdx.x;

    for (int j = tid; j < NFFT; j += 256) {
        int jj = (j <= 512) ? j : 1024 - j;
        float2 v = ms[b * NF + jj];
        if (j > 512) v.y = -v.y;
        FD[pd(__brev(j) >> 22)] = v;
    }
    __syncthreads();

    for (int lg = 0; lg <= 9; ++lg) {
        const int len = 1 << lg;
        for (int pr = tid; pr < 512; pr += 256) {
            const int jj = pr & (len - 1);
            const int i0 = ((pr >> lg) << (lg + 1)) + jj;
            const int i1 = i0 + len;
            const int iw = jj << (9 - lg);
            float sn, cs;
            __sincosf(-PI2 * (1.0f / 1024.0f) * (float)iw, &sn, &cs);
            float2 a = FD[pd(i0)], bb = FD[pd(i1)];
            float tr = bb.x * cs + bb.y * sn;
            float ti = bb.y * cs - bb.x * sn;
            FD[pd(i0)] = make_float2(a.x + tr, a.y + ti);
            FD[pd(i1)] = make_float2(a.x - tr, a.y - ti);
        }
        __syncthreads();
    }
    for (int t = tid; t < NFFT; t += 256)
        out[b * NFFT + t] = FD[pd(t)].x * (1.0f / 1024.0f);
}

extern "C" void kernel_launch(void* const* d_in, const int* in_sizes, int n_in,
                              void* d_out, int out_size, void* d_ws, size_t ws_size,
                              hipStream_t stream)
{
    const float* tf    = (const float*)d_in[1];
    const float* imp   = (const float*)d_in[2];
    const float* noise = (const float*)d_in[3];
    float* out = (float*)d_out;

    unsigned* Et  = (unsigned*)d_ws;                              // 16*256*1024*8 u32
    unsigned* TFt = Et + (size_t)16 * 256 * 1024 * 8;             // 16*257*4096 u32
    float2*   ms  = (float2*)(TFt + (size_t)16 * NKP * NCELLS);   // 16*513 c64

    k_p1<<<4096, 256, 0, stream>>>(tf, imp, noise, Et, TFt);
    k_p2<<<512, 1024, 0, stream>>>(Et, TFt, ms);
    k_p3<<<16, 256, 0, stream>>>(ms, out);
}

// Round 14
// 284.457 us; speedup vs baseline: 1.1007x; 1.1007x over previous
//
#include <hip/hip_runtime.h>

// Frequency-domain room sim, 3-kernel phase split.
//   SF = DFT(sound_field) per cell (unnormalized); per block b:
//     T = clip(res,0,1) * (SF + DFT(env_b));  mic_b = IDFT(T[mic])/1024;
//     SF = box3x3x3(T)   (pointwise per bin -> recursion independent per bin)
// P1: radix-4^5 env FFTs, 4 points/thread, 4 cells/WG (2 packed complex per
//     float4 lane), ONE 16 KB LDS buffer -> 8 WG/CU = 32 waves/CU (100%
//     occupancy; rounds 10-13 showed k_p1 is wave-starved latency-bound at
//     3.4 waves/SIMD). env+pass0 in registers; 4 LDS round-trip passes;
//     5 barriers. Base-4 digit-reversed slot order. XCD-chunked swizzle.
// P2: 512 WGs x 1024 threads (round-12 form). Thread owns 4-z slab; z via
//     shfl, y/x via 32KB swizzled LDS. WG0 = bins {0,512} packed real pair.
// P3: 16 inverse FFTs of the mic spectra.

#define NFFT   1024
#define NF     513
#define NKP    257
#define NCELLS 4096
#define NPAIR  2048
#define PI2    6.28318530717958647692f

// base-4 digit reversal of a 10-bit index (5 digits)
__device__ __forceinline__ int slotof4(int k) {
    return ((k & 3) << 8) | (((k >> 2) & 3) << 6) | (((k >> 4) & 3) << 4) |
           (((k >> 6) & 3) << 2) | ((k >> 8) & 3);
}
__device__ __forceinline__ float clip01(float v) { return fminf(fmaxf(v, 0.0f), 1.0f); }
__device__ __forceinline__ unsigned pkh2(float a, float b) {
    union { _Float16 h[2]; unsigned u; } z;
    z.h[0] = (_Float16)a; z.h[1] = (_Float16)b;
    return z.u;
}
__device__ __forceinline__ float h2lo(unsigned u) {
    union { unsigned u; _Float16 h[2]; } z; z.u = u; return (float)z.h[0];
}
__device__ __forceinline__ float h2hi(unsigned u) {
    union { unsigned u; _Float16 h[2]; } z; z.u = u; return (float)z.h[1];
}
__device__ __forceinline__ unsigned cmp4(const uint4& v, int c) {
    return c == 0 ? v.x : c == 1 ? v.y : c == 2 ? v.z : v.w;
}
__device__ __forceinline__ float4 f4add(float4 a, float4 b) {
    return make_float4(a.x + b.x, a.y + b.y, a.z + b.z, a.w + b.w);
}
__device__ __forceinline__ float4 f4sub(float4 a, float4 b) {
    return make_float4(a.x - b.x, a.y - b.y, a.z - b.z, a.w - b.w);
}
__device__ __forceinline__ float4 cmul2(float4 d, float2 w) {
    return make_float4(d.x * w.x - d.y * w.y, d.x * w.y + d.y * w.x,
                       d.z * w.x - d.w * w.y, d.z * w.y + d.w * w.x);
}
__device__ __forceinline__ float4 nI(float4 v) { return make_float4(v.y, -v.x, v.w, -v.z); }
__device__ __forceinline__ float4 pI(float4 v) { return make_float4(-v.y, v.x, -v.w, v.z); }

// in-register radix-4 DFT on 2 packed complexes: a[p] <- sum_m a[m] W4^{pm}
__device__ __forceinline__ void dft4(float4* a) {
    float4 e = f4add(a[0], a[2]), f = f4add(a[1], a[3]);
    float4 g = f4sub(a[0], a[2]), h = f4sub(a[1], a[3]);
    a[0] = f4add(e, f);
    a[2] = f4sub(e, f);
    a[1] = f4add(g, nI(h));
    a[3] = f4add(g, pI(h));
}

// a[p] *= W_{4s}^{j*p}, p = 1..3 (chained)
__device__ __forceinline__ void twiddle3(float4* a, int j, float invL) {
    float sv, cv;
    __sincosf(-PI2 * (float)j * invL, &sv, &cv);
    float2 w1 = make_float2(cv, sv), wp = w1;
    a[1] = cmul2(a[1], wp);
    wp = make_float2(wp.x * w1.x - wp.y * w1.y, wp.x * w1.y + wp.y * w1.x);
    a[2] = cmul2(a[2], wp);
    wp = make_float2(wp.x * w1.x - wp.y * w1.y, wp.x * w1.y + wp.y * w1.x);
    a[3] = cmul2(a[3], wp);
}

// ---------------- P1 ----------------
// Grid 16384 = 16 blocks x 1024 groups of 4 cells. 256 threads, 4 pts/thread.
__global__ __launch_bounds__(256, 8) void k_p1(
    const float* __restrict__ tf, const float* __restrict__ imp,
    const float* __restrict__ noise, unsigned* __restrict__ Et,
    unsigned* __restrict__ TFt)
{
    __shared__ float4 FD[1024];        // exactly 16 KB -> 8 WG/CU (wave cap)

    const int tid = threadIdx.x;
    const int bid = blockIdx.x;
    const int w   = ((bid & 7) << 11) | (bid >> 3);   // XCD-chunked swizzle
    const int b   = w >> 10;
    const int c0  = (w & 1023) << 2;

    // ---- env + pass0 (s=256) entirely from registers ----
    {
        const float* nz = noise + ((size_t)b * NCELLS + c0) * (size_t)NFFT;
        float nzv[16];
        #pragma unroll
        for (int m = 0; m < 4; ++m) {
            #pragma unroll
            for (int cc = 0; cc < 4; ++cc)
                nzv[4 * m + cc] = nz[cc * NFFT + tid + (m << 8)];
        }
        const float* ipr = imp + ((size_t)b * NCELLS + c0) * 16;
        float4 a[4];
        #pragma unroll
        for (int m = 0; m < 4; ++m) {
            int n = tid + (m << 8);
            float coord = (n + 0.5f) * (16.0f / 1024.0f) - 0.5f;
            coord = fminf(fmaxf(coord, 0.0f), 15.0f);
            int lo = (int)coord;
            int hi = lo + 1 > 15 ? 15 : lo + 1;
            float wl = coord - (float)lo, wh = 1.0f - wl;
            float4 e;
            e.x = clip01(ipr[lo]      * wh + ipr[hi]      * wl) * nzv[4 * m + 0];
            e.y = clip01(ipr[16 + lo] * wh + ipr[16 + hi] * wl) * nzv[4 * m + 1];
            e.z = clip01(ipr[32 + lo] * wh + ipr[32 + hi] * wl) * nzv[4 * m + 2];
            e.w = clip01(ipr[48 + lo] * wh + ipr[48 + hi] * wl) * nzv[4 * m + 3];
            a[m] = e;
        }
        dft4(a);
        twiddle3(a, tid, 1.0f / 1024.0f);
        #pragma unroll
        for (int p = 0; p < 4; ++p) FD[tid + (p << 8)] = a[p];
    }
    __syncthreads();

    // ---- passes s = 64, 16, 4 ----
    #pragma unroll
    for (int pi = 0; pi < 3; ++pi) {
        const int lgs = 6 - 2 * pi;
        const int s   = 1 << lgs;
        const int j   = tid & (s - 1);
        const int idx0 = ((tid >> lgs) << (lgs + 2)) | j;
        float4 a[4];
        #pragma unroll
        for (int m = 0; m < 4; ++m) a[m] = FD[idx0 + (m << lgs)];
        dft4(a);
        twiddle3(a, j, 1.0f / (float)(s << 2));
        #pragma unroll
        for (int p = 0; p < 4; ++p) FD[idx0 + (p << lgs)] = a[p];
        __syncthreads();
    }

    // ---- pass s=1 (trivial twiddle) ----
    {
        const int idx0 = tid << 2;
        float4 a[4];
        #pragma unroll
        for (int m = 0; m < 4; ++m) a[m] = FD[idx0 + m];
        dft4(a);
        #pragma unroll
        for (int p = 0; p < 4; ++p) FD[idx0 + p] = a[p];
    }
    __syncthreads();

    // ---- extract sweep: linear slot read -> fp16 pack -> 8B store/lane ----
    {
        unsigned* base = Et + (size_t)b * NFFT * NPAIR + (c0 >> 1);
        #pragma unroll
        for (int it = 0; it < 4; ++it) {
            int s = tid + (it << 8);
            float4 v = FD[s];
            uint2 u = { pkh2(v.x, v.y), pkh2(v.z, v.w) };
            *(uint2*)(base + (size_t)s * NPAIR) = u;
        }
    }

    // ---- tf: clip + pack bin pairs for 4 cells ----
    {
        const float* r0 = tf + ((size_t)b * NCELLS + c0) * NF;
        const float* r1 = r0 + NF;
        const float* r2 = r1 + NF;
        const float* r3 = r2 + NF;
        for (int kp = tid; kp < NKP; kp += 256) {
            bool hv = kp < 256;
            uint4 u;
            u.x = pkh2(clip01(r0[2 * kp]), hv ? clip01(r0[2 * kp + 1]) : 0.0f);
            u.y = pkh2(clip01(r1[2 * kp]), hv ? clip01(r1[2 * kp + 1]) : 0.0f);
            u.z = pkh2(clip01(r2[2 * kp]), hv ? clip01(r2[2 * kp + 1]) : 0.0f);
            u.w = pkh2(clip01(r3[2 * kp]), hv ? clip01(r3[2 * kp + 1]) : 0.0f);
            *(uint4*)(TFt + ((size_t)b * NKP + kp) * NCELLS + c0) = u;
        }
    }
}

// ---------------- P2 ----------------
// Grid 512 x 1024 threads. Thread q: x = q>>6, y = (q>>2)&15, z-slab (q&3)*4;
// pairs 2q,2q+1. z-exchange via in-wave shfl; y/x via 32KB swizzled LDS.
// WG0 = bins {0,512} (both exactly real), rows slotof4(0)=0 / slotof4(512)=2.
__global__ __launch_bounds__(1024, 8) void k_p2(
    const unsigned* __restrict__ Et, const unsigned* __restrict__ TFt,
    float2* __restrict__ ms)
{
    __shared__ float2 Sz[4096];        // 32 KB

    const int q    = threadIdx.x;
    const int lane = q & 63;
    const int k    = blockIdx.x;
    const bool dual = (k == 0);
    const int kp  = dual ? 0 : (k >> 1);
    const int sel = dual ? 0 : (k & 1);
    const int rA  = slotof4(dual ? 0 : k);
    const int rB  = slotof4(dual ? 512 : ((1024 - k) & 1023));
    const int x = q >> 6, y = (q >> 2) & 15, zs = (q & 3) << 2;

    #define AX(qq, dz) (((qq) << 2) | ((dz) ^ ((qq) & 3) ^ (((qq) >> 2) & 3)))

    float2 SF[4];
    #pragma unroll
    for (int dz = 0; dz < 4; ++dz) SF[dz] = make_float2(0.f, 0.f);

    #pragma unroll 1
    for (int b = 0; b < 16; ++b) {
        const uint2 ea = *(const uint2*)(Et + ((size_t)b * NFFT + rA) * NPAIR + 2 * q);
        const uint2 eb = *(const uint2*)(Et + ((size_t)b * NFFT + rB) * NPAIR + 2 * q);
        const uint4 tp = *(const uint4*)(TFt + ((size_t)b * NKP + kp) * NCELLS + 4 * q);
        uint4 tp2;
        if (dual) tp2 = *(const uint4*)(TFt + ((size_t)b * NKP + 256) * NCELLS + 4 * q);

        float2 T[4];
        if (!dual) {
            #pragma unroll
            for (int j = 0; j < 2; ++j) {
                unsigned fu = j ? ea.y : ea.x;
                unsigned gu = j ? eb.y : eb.x;
                float fr = h2lo(fu), fi = h2hi(fu);
                float gr = h2lo(gu), gi = h2hi(gu);
                float ear = 0.5f * (fr + gr), eai = 0.5f * (fi - gi);
                float ebr = 0.5f * (fi + gi), ebi = 0.5f * (gr - fr);
                unsigned te = cmp4(tp, 2 * j);
                unsigned to = cmp4(tp, 2 * j + 1);
                float re_ = sel ? h2hi(te) : h2lo(te);
                float ro_ = sel ? h2hi(to) : h2lo(to);
                T[2 * j]     = make_float2(re_ * (SF[2 * j].x + ear),
                                           re_ * (SF[2 * j].y + eai));
                T[2 * j + 1] = make_float2(ro_ * (SF[2 * j + 1].x + ebr),
                                           ro_ * (SF[2 * j + 1].y + ebi));
            }
        } else {
            #pragma unroll
            for (int dz = 0; dz < 4; ++dz) {
                unsigned fu = (dz >> 1) ? ea.y : ea.x;
                unsigned gu = (dz >> 1) ? eb.y : eb.x;
                float e0   = (dz & 1) ? h2hi(fu) : h2lo(fu);
                float e512 = (dz & 1) ? h2hi(gu) : h2lo(gu);
                float tA = h2lo(cmp4(tp, dz));
                float tB = h2lo(cmp4(tp2, dz));
                T[dz] = make_float2(tA * (SF[dz].x + e0),
                                    tB * (SF[dz].y + e512));
            }
        }
        if (q == 546) {                 // cell (8,8,8)
            if (dual) {
                ms[b * NF + 0]   = make_float2(T[0].x, 0.0f);
                ms[b * NF + 512] = make_float2(T[0].y, 0.0f);
            } else {
                ms[b * NF + k] = T[0];
            }
        }

        // z-sum: slab-internal + shfl partners q-1 / q+1
        float2 D, U;
        D.x = __shfl(T[3].x, lane - 1, 64); D.y = __shfl(T[3].y, lane - 1, 64);
        U.x = __shfl(T[0].x, lane + 1, 64); U.y = __shfl(T[0].y, lane + 1, 64);
        float2 Z[4];
        Z[0] = make_float2(T[0].x + T[1].x + (zs > 0 ? D.x : 0.f),
                           T[0].y + T[1].y + (zs > 0 ? D.y : 0.f));
        Z[1] = make_float2(T[0].x + T[1].x + T[2].x, T[0].y + T[1].y + T[2].y);
        Z[2] = make_float2(T[1].x + T[2].x + T[3].x, T[1].y + T[2].y + T[3].y);
        Z[3] = make_float2(T[2].x + T[3].x + (zs < 12 ? U.x : 0.f),
                           T[2].y + T[3].y + (zs < 12 ? U.y : 0.f));

        // y-sum via LDS (neighbor q +- 4)
        #pragma unroll
        for (int dz = 0; dz < 4; ++dz) Sz[AX(q, dz)] = Z[dz];
        __syncthreads();
        #pragma unroll
        for (int dz = 0; dz < 4; ++dz) {
            float2 s = Z[dz];
            if (y > 0)  { float2 u = Sz[AX(q - 4, dz)]; s.x += u.x; s.y += u.y; }
            if (y < 15) { float2 u = Sz[AX(q + 4, dz)]; s.x += u.x; s.y += u.y; }
            Z[dz] = s;
        }
        __syncthreads();
        // x-sum via LDS (neighbor q +- 64)
        #pragma unroll
        for (int dz = 0; dz < 4; ++dz) Sz[AX(q, dz)] = Z[dz];
        __syncthreads();
        #pragma unroll
        for (int dz = 0; dz < 4; ++dz) {
            float2 s = Z[dz];
            if (x > 0)  { float2 u = Sz[AX(q - 64, dz)]; s.x += u.x; s.y += u.y; }
            if (x < 15) { float2 u = Sz[AX(q + 64, dz)]; s.x += u.x; s.y += u.y; }
            SF[dz] = s;
        }
        __syncthreads();
    }
    #undef AX
}

// ---------------- P3 ----------------
__device__ __forceinline__ int pd(int i) { return i + (i >> 5); }

__global__ __launch_bounds__(256) void k_p3(
    const float2* __restrict__ ms, float* __restrict__ out)
{
    __shared__ float2 FD[1056];
    const int b = blockIdx.x, tid = threadIdx.x;

    for (int j = tid; j < NFFT; j += 256) {
        int jj = (j <= 512) ? j : 1024 - j;
        float2 v = ms[b * NF + jj];
        if (j > 512) v.y = -v.y;
        FD[pd(__brev(j) >> 22)] = v;
    }
    __syncthreads();

    for (int lg = 0; lg <= 9; ++lg) {
        const int len = 1 << lg;
        for (int pr = tid; pr < 512; pr += 256) {
            const int jj = pr & (len - 1);
            const int i0 = ((pr >> lg) << (lg + 1)) + jj;
            const int i1 = i0 + len;
            const int iw = jj << (9 - lg);
            float sn, cs;
            __sincosf(-PI2 * (1.0f / 1024.0f) * (float)iw, &sn, &cs);
            float2 a = FD[pd(i0)], bb = FD[pd(i1)];
            float tr = bb.x * cs + bb.y * sn;
            float ti = bb.y * cs - bb.x * sn;
            FD[pd(i0)] = make_float2(a.x + tr, a.y + ti);
            FD[pd(i1)] = make_float2(a.x - tr, a.y - ti);
        }
        __syncthreads();
    }
    for (int t = tid; t < NFFT; t += 256)
        out[b * NFFT + t] = FD[pd(t)].x * (1.0f / 1024.0f);
}

extern "C" void kernel_launch(void* const* d_in, const int* in_sizes, int n_in,
                              void* d_out, int out_size, void* d_ws, size_t ws_size,
                              hipStream_t stream)
{
    const float* tf    = (const float*)d_in[1];
    const float* imp   = (const float*)d_in[2];
    const float* noise = (const float*)d_in[3];
    float* out = (float*)d_out;

    unsigned* Et  = (unsigned*)d_ws;                              // 16*1024*2048 u32
    unsigned* TFt = Et + (size_t)16 * NFFT * NPAIR;               // 16*257*4096 u32
    float2*   ms  = (float2*)(TFt + (size_t)16 * NKP * NCELLS);   // 16*513 c64

    k_p1<<<16384, 256, 0, stream>>>(tf, imp, noise, Et, TFt);
    k_p2<<<512, 1024, 0, stream>>>(Et, TFt, ms);
    k_p3<<<16, 256, 0, stream>>>(ms, out);
}